// Round 1
// baseline (273.924 us; speedup 1.0000x reference)
//
#include <hip/hip_runtime.h>
#include <stdint.h>

typedef unsigned short ushort_t;
typedef float f32x4 __attribute__((ext_vector_type(4)));
typedef short bf16x8 __attribute__((ext_vector_type(8)));
typedef unsigned short us8 __attribute__((ext_vector_type(8)));

#define BATCH 8
#define SEQ   2048
#define DIM   512
#define MBLK  64
#define KBLK  32
#define NIT   (SEQ / KBLK)

// ---------- helpers ----------
__device__ __forceinline__ ushort_t f2bf(float f) {
  union { float f; uint32_t u; } c; c.f = f;
  uint32_t u = c.u;
  uint32_t r = (u + 0x7FFFu + ((u >> 16) & 1u)) >> 16;  // RNE
  return (ushort_t)r;
}
__device__ __forceinline__ uint32_t packbf(float a, float b) {
  return (uint32_t)f2bf(a) | ((uint32_t)f2bf(b) << 16);
}
__device__ __forceinline__ void gload_lds16(const void* g, void* l) {
  __builtin_amdgcn_global_load_lds(
      (const __attribute__((address_space(1))) unsigned int*)g,
      (__attribute__((address_space(3))) unsigned int*)l, 16, 0, 0);
}

// ---------- kernel 1: L2-normalize rows, scale by sqrt(log2 e), cast bf16 ----------
__global__ void k_norm(const float* __restrict__ x, ushort_t* __restrict__ xn) {
  const int lane = threadIdx.x & 63;
  const int wid  = threadIdx.x >> 6;
  const size_t row = (size_t)blockIdx.x * 4 + wid;   // 16384 rows
  const float* xr = x + row * DIM;
  const float4 a = ((const float4*)xr)[lane * 2];
  const float4 b = ((const float4*)xr)[lane * 2 + 1];
  float ss = a.x*a.x + a.y*a.y + a.z*a.z + a.w*a.w
           + b.x*b.x + b.y*b.y + b.z*b.z + b.w*b.w;
#pragma unroll
  for (int m = 32; m >= 1; m >>= 1) ss += __shfl_xor(ss, m, 64);
  // sqrt(log2(e)) = 1.20112240878... ; S = (q.k)*log2e comes out of MFMA directly
  const float rn = 1.2011224087864498f / sqrtf(fmaxf(ss, 1e-30f));
  us8 o;
  o[0] = f2bf(a.x*rn); o[1] = f2bf(a.y*rn); o[2] = f2bf(a.z*rn); o[3] = f2bf(a.w*rn);
  o[4] = f2bf(b.x*rn); o[5] = f2bf(b.y*rn); o[6] = f2bf(b.z*rn); o[7] = f2bf(b.w*rn);
  *(us8*)(xn + row * DIM + lane * 8) = o;
}

// ---------- kernel 2: V^T (bf16): vt[b][d][n] = x[b][n][d] ----------
__global__ void k_transpose(const float* __restrict__ x, ushort_t* __restrict__ vt) {
  __shared__ __align__(16) ushort_t tile[64][72];   // pad: 144B row stride, 16B aligned
  const int t   = threadIdx.x;
  const int bid = blockIdx.x;
  const int b   = bid >> 8;          // 256 tiles per batch (32 n-tiles x 8 d-tiles)
  const int nt  = (bid >> 3) & 31;
  const int dt  = bid & 7;
  const size_t n0 = (size_t)nt * 64, d0 = (size_t)dt * 64;
  const float* xb = x + ((size_t)b * SEQ + n0) * DIM + d0;
#pragma unroll
  for (int p = 0; p < 4; ++p) {
    const int r  = p * 16 + (t >> 4);
    const int c4 = t & 15;
    const float4 v = *(const float4*)(xb + (size_t)r * DIM + c4 * 4);
    tile[c4*4+0][r] = f2bf(v.x);
    tile[c4*4+1][r] = f2bf(v.y);
    tile[c4*4+2][r] = f2bf(v.z);
    tile[c4*4+3][r] = f2bf(v.w);
  }
  __syncthreads();
  ushort_t* vb = vt + ((size_t)b * DIM + d0) * SEQ + n0;
  const int dd = t >> 2;
#pragma unroll
  for (int e = 0; e < 2; ++e) {
    const int c = (t & 3) * 2 + e;
    us8 v = *(const us8*)(&tile[dd][c * 8]);
    *(us8*)(vb + (size_t)dd * SEQ + c * 8) = v;
  }
}

// ---------- kernel 3: fused flash ContraNorm ----------
// 256 blocks: b = bid&7 (XCD affinity), qtile = bid>>3. 4 waves (mw, nw):
//   mw = row half (32 rows each), nw = key half for QK^T / d half (256) for PV.
// LDS: P[64][32]bf16 @0 (4KB) | mstat @4096 | sstat @4608 | K0 @8192 | K1 @40960
//      | V0 @73728 | V1 @106496 ; total 139264 B.
__launch_bounds__(256, 1)
__global__ void k_attn(const ushort_t* __restrict__ xn, const ushort_t* __restrict__ vt,
                       const float* __restrict__ x, float* __restrict__ out) {
  extern __shared__ char smem[];
  ushort_t* Plds = (ushort_t*)smem;            // [64 q][32 key]
  float* mstat = (float*)(smem + 4096);        // [2 mw][2 nw][32 q]
  float* sstat = (float*)(smem + 4608);
  char* const Kb0 = smem + 8192;
  char* const Kb1 = smem + 8192 + 32768;
  char* const Vb0 = smem + 73728;
  char* const Vb1 = smem + 73728 + 32768;

  const int tid  = threadIdx.x;
  const int lane = tid & 63, wid = tid >> 6;
  const int mw = wid >> 1, nw = wid & 1;
  const int b  = blockIdx.x & 7, qt = blockIdx.x >> 3;
  const int q0 = qt * MBLK;
  const int ql = lane & 15, qg = lane >> 4;

  const ushort_t* xnb = xn + (size_t)b * SEQ * DIM;
  const ushort_t* vtb = vt + (size_t)b * DIM * SEQ;

  // Q fragments in registers: rows mw*32 + h*16 + ql, all 512 d (16 ksteps)
  bf16x8 qreg[2][16];
#pragma unroll
  for (int h = 0; h < 2; ++h)
#pragma unroll
    for (int ks = 0; ks < 16; ++ks)
      qreg[h][ks] = *(const bf16x8*)(xnb + (size_t)(q0 + mw*32 + h*16 + ql) * DIM + ks*32 + qg*8);

  f32x4 acc[16][2];
#pragma unroll
  for (int ds = 0; ds < 16; ++ds)
#pragma unroll
    for (int m = 0; m < 2; ++m) acc[ds][m] = (f32x4){0.f, 0.f, 0.f, 0.f};
  float mrun0 = -3.0e38f, mrun1 = -3.0e38f, lrun0 = 0.f, lrun1 = 0.f;

  auto stage = [&](int it, char* Kb, char* Vb) {
    const int k0 = it * KBLK;
    // K tile [32 key][512 d], source pre-swizzled (chunk ^= key&7) for conflict-free reads
#pragma unroll
    for (int c = 0; c < 8; ++c) {
      const int idx = c * 256 + tid;
      const int kky = idx >> 6, dc = idx & 63;
      const ushort_t* g = xnb + (size_t)(k0 + kky) * DIM + ((dc ^ (kky & 7)) << 3);
      gload_lds16(g, Kb + (c * 256 + wid * 64) * 16);
    }
    // V^T tile [512 d][32 key], linear
#pragma unroll
    for (int c = 0; c < 8; ++c) {
      const int idx = c * 256 + tid;
      const int d = idx >> 2, kc = idx & 3;
      const ushort_t* g = vtb + (size_t)d * SEQ + k0 + kc * 8;
      gload_lds16(g, Vb + (c * 256 + wid * 64) * 16);
    }
  };

  stage(0, Kb0, Vb0);
  asm volatile("s_waitcnt vmcnt(0)" ::: "memory");
  __builtin_amdgcn_s_barrier();
  asm volatile("" ::: "memory");

  for (int t = 0; t < NIT; ++t) {
    char* Kc = (t & 1) ? Kb1 : Kb0;
    char* Vc = (t & 1) ? Vb1 : Vb0;
    if (t + 1 < NIT) stage(t + 1, (t & 1) ? Kb0 : Kb1, (t & 1) ? Vb0 : Vb1);

    // ---- S^T = K . Q^T : C'[key][q], keys nw*16..+16, q cols mw*32 + h*16 ----
    const int key = nw * 16 + ql;
    f32x4 c0 = (f32x4){0.f,0.f,0.f,0.f}, c1 = (f32x4){0.f,0.f,0.f,0.f};
#pragma unroll
    for (int ks = 0; ks < 16; ++ks) {
      const int chunk = ks * 4 + qg;
      bf16x8 af = *(const bf16x8*)(Kc + key * 1024 + ((chunk ^ (key & 7)) << 4));
      c0 = __builtin_amdgcn_mfma_f32_16x16x32_bf16(af, qreg[0][ks], c0, 0, 0, 0);
      c1 = __builtin_amdgcn_mfma_f32_16x16x32_bf16(af, qreg[1][ks], c1, 0, 0, 0);
    }
    // ---- per-q max over this wave's 16 keys (regs = keys, lanes&15 = q) ----
    float mt0 = fmaxf(fmaxf(c0[0], c0[1]), fmaxf(c0[2], c0[3]));
    float mt1 = fmaxf(fmaxf(c1[0], c1[1]), fmaxf(c1[2], c1[3]));
    mt0 = fmaxf(mt0, __shfl_xor(mt0, 16, 64)); mt0 = fmaxf(mt0, __shfl_xor(mt0, 32, 64));
    mt1 = fmaxf(mt1, __shfl_xor(mt1, 16, 64)); mt1 = fmaxf(mt1, __shfl_xor(mt1, 32, 64));
    if (lane < 32) mstat[(mw * 2 + nw) * 32 + lane] = (lane < 16) ? mt0 : mt1;
    asm volatile("s_waitcnt lgkmcnt(0)" ::: "memory");
    __builtin_amdgcn_s_barrier();
    asm volatile("" ::: "memory");
    const float mo0 = mstat[(mw * 2 + (nw ^ 1)) * 32 + ql];
    const float mo1 = mstat[(mw * 2 + (nw ^ 1)) * 32 + 16 + ql];
    const float mn0 = fmaxf(fmaxf(mt0, mo0), mrun0);
    const float mn1 = fmaxf(fmaxf(mt1, mo1), mrun1);
    const float sc0 = __builtin_amdgcn_exp2f(mrun0 - mn0);
    const float sc1 = __builtin_amdgcn_exp2f(mrun1 - mn1);
    mrun0 = mn0; mrun1 = mn1;
    f32x4 p0, p1;
#pragma unroll
    for (int j = 0; j < 4; ++j) {
      p0[j] = __builtin_amdgcn_exp2f(c0[j] - mn0);
      p1[j] = __builtin_amdgcn_exp2f(c1[j] - mn1);
    }
    float s0 = p0[0] + p0[1] + p0[2] + p0[3];
    float s1 = p1[0] + p1[1] + p1[2] + p1[3];
    s0 += __shfl_xor(s0, 16, 64); s0 += __shfl_xor(s0, 32, 64);
    s1 += __shfl_xor(s1, 16, 64); s1 += __shfl_xor(s1, 32, 64);
    if (lane < 32) sstat[(mw * 2 + nw) * 32 + lane] = (lane < 16) ? s0 : s1;
    // P -> LDS [q][key], bf16, pairs packed as b32
    {
      uint32_t* w0 = (uint32_t*)(Plds + (mw * 32 + ql) * 32 + nw * 16 + qg * 4);
      w0[0] = packbf(p0[0], p0[1]); w0[1] = packbf(p0[2], p0[3]);
      uint32_t* w1 = (uint32_t*)(Plds + (mw * 32 + 16 + ql) * 32 + nw * 16 + qg * 4);
      w1[0] = packbf(p1[0], p1[1]); w1[1] = packbf(p1[2], p1[3]);
    }
    asm volatile("s_waitcnt lgkmcnt(0)" ::: "memory");
    __builtin_amdgcn_s_barrier();
    asm volatile("" ::: "memory");
    const float so0 = sstat[(mw * 2 + (nw ^ 1)) * 32 + ql];
    const float so1 = sstat[(mw * 2 + (nw ^ 1)) * 32 + 16 + ql];
    lrun0 = lrun0 * sc0 + s0 + so0;
    lrun1 = lrun1 * sc1 + s1 + so1;
    // rescale acc: need sc at q = m*16 + qg*4 + r  (softmax had q at lane&15)
    float sca[2][4];
#pragma unroll
    for (int r = 0; r < 4; ++r) {
      sca[0][r] = __shfl(sc0, qg * 4 + r, 16);
      sca[1][r] = __shfl(sc1, qg * 4 + r, 16);
    }
#pragma unroll
    for (int ds = 0; ds < 16; ++ds)
#pragma unroll
      for (int m = 0; m < 2; ++m)
#pragma unroll
        for (int r = 0; r < 4; ++r) acc[ds][m][r] *= sca[m][r];
    // ---- PV: O[q][d], this wave's d-half = nw*256 ----
    bf16x8 pa0 = *(const bf16x8*)(Plds + (mw * 32 + ql) * 32 + qg * 8);
    bf16x8 pa1 = *(const bf16x8*)(Plds + (mw * 32 + 16 + ql) * 32 + qg * 8);
#pragma unroll
    for (int ds = 0; ds < 16; ++ds) {
      bf16x8 vb = *(const bf16x8*)(Vc + ((size_t)(nw * 256 + ds * 16 + ql) * 32 + qg * 8) * 2);
      acc[ds][0] = __builtin_amdgcn_mfma_f32_16x16x32_bf16(pa0, vb, acc[ds][0], 0, 0, 0);
      acc[ds][1] = __builtin_amdgcn_mfma_f32_16x16x32_bf16(pa1, vb, acc[ds][1], 0, 0, 0);
    }
    asm volatile("s_waitcnt vmcnt(0) lgkmcnt(0)" ::: "memory");
    __builtin_amdgcn_s_barrier();
    asm volatile("" ::: "memory");
  }

  // ---- epilogue: out = 1.2 x - (0.2/l) * acc ----
  float iv[2][4];
#pragma unroll
  for (int r = 0; r < 4; ++r) {
    iv[0][r] = 0.2f / __shfl(lrun0, qg * 4 + r, 16);
    iv[1][r] = 0.2f / __shfl(lrun1, qg * 4 + r, 16);
  }
  const float* xb = x   + ((size_t)b * SEQ + q0 + mw * 32) * DIM;
  float*       ob = out + ((size_t)b * SEQ + q0 + mw * 32) * DIM;
#pragma unroll
  for (int ds = 0; ds < 16; ++ds)
#pragma unroll
    for (int m = 0; m < 2; ++m)
#pragma unroll
      for (int r = 0; r < 4; ++r) {
        const int q = m * 16 + qg * 4 + r;
        const int d = nw * 256 + ds * 16 + ql;
        const float xv = xb[(size_t)q * DIM + d];
        ob[(size_t)q * DIM + d] = 1.2f * xv - iv[m][r] * acc[ds][m][r];
      }
}

extern "C" void kernel_launch(void* const* d_in, const int* in_sizes, int n_in,
                              void* d_out, int out_size, void* d_ws, size_t ws_size,
                              hipStream_t stream) {
  const float* x = (const float*)d_in[0];
  float* out = (float*)d_out;
  ushort_t* xn = (ushort_t*)d_ws;                                          // 16 MB
  ushort_t* vt = (ushort_t*)((char*)d_ws + (size_t)BATCH * SEQ * DIM * 2); // 16 MB

  k_norm<<<BATCH * SEQ / 4, 256, 0, stream>>>(x, xn);
  k_transpose<<<BATCH * (SEQ / 64) * (DIM / 64), 256, 0, stream>>>(x, vt);
  (void)hipFuncSetAttribute((const void*)k_attn,
                            hipFuncAttributeMaxDynamicSharedMemorySize, 139264);
  k_attn<<<BATCH * SEQ / MBLK, 256, 139264, stream>>>(xn, vt, x, out);
}

// Round 2
// 226.376 us; speedup vs baseline: 1.2100x; 1.2100x over previous
//
#include <hip/hip_runtime.h>
#include <stdint.h>

typedef unsigned short ushort_t;
typedef float f32x2 __attribute__((ext_vector_type(2)));
typedef float f32x4 __attribute__((ext_vector_type(4)));
typedef float f32x16 __attribute__((ext_vector_type(16)));
typedef short bf16x8 __attribute__((ext_vector_type(8)));
typedef unsigned short us8 __attribute__((ext_vector_type(8)));

#define BATCH 8
#define SEQ   2048
#define DIM   512
#define KBLK  64
#define NIT   (SEQ / KBLK)
#define LDS_TOTAL 156160

// ---------- helpers ----------
__device__ __forceinline__ ushort_t f2bf(float f) {
  union { float f; uint32_t u; } c; c.f = f;
  uint32_t u = c.u;
  return (ushort_t)((u + 0x7FFFu + ((u >> 16) & 1u)) >> 16);  // RNE
}
__device__ __forceinline__ uint32_t packbf(float a, float b) {
  return (uint32_t)f2bf(a) | ((uint32_t)f2bf(b) << 16);
}
__device__ __forceinline__ void gload_lds16(const void* g, void* l) {
  __builtin_amdgcn_global_load_lds(
      (const __attribute__((address_space(1))) unsigned int*)g,
      (__attribute__((address_space(3))) unsigned int*)l, 16, 0, 0);
}
#define WAIT_LGKM_BAR() { asm volatile("s_waitcnt lgkmcnt(0)" ::: "memory"); \
  __builtin_amdgcn_s_barrier(); __builtin_amdgcn_sched_barrier(0); }
#define WAIT_ALL_BAR()  { asm volatile("s_waitcnt vmcnt(0) lgkmcnt(0)" ::: "memory"); \
  __builtin_amdgcn_s_barrier(); __builtin_amdgcn_sched_barrier(0); }

// ---------- kernel 1: fused L2-normalize (-> xn bf16, scaled by sqrt(log2 e))
// ---------- and raw-x transpose (-> vt bf16 [b][d][n]) ----------
__global__ void k_prep(const float* __restrict__ x, ushort_t* __restrict__ xn,
                       ushort_t* __restrict__ vt) {
  __shared__ __align__(16) ushort_t tile[64][512];  // raw bf16 [n][d], 64KB
  const int tid = threadIdx.x, lane = tid & 63, w = tid >> 6;
  const int b = blockIdx.x >> 5, nt = blockIdx.x & 31;
  const size_t row0 = (size_t)b * SEQ + (size_t)nt * 64;

  for (int j = 0; j < 16; ++j) {
    const int r = w * 16 + j;
    const float* xr = x + (row0 + r) * DIM;
    const float4 a  = ((const float4*)xr)[lane * 2];
    const float4 bb = ((const float4*)xr)[lane * 2 + 1];
    float ss = a.x*a.x + a.y*a.y + a.z*a.z + a.w*a.w
             + bb.x*bb.x + bb.y*bb.y + bb.z*bb.z + bb.w*bb.w;
#pragma unroll
    for (int m = 32; m >= 1; m >>= 1) ss += __shfl_xor(ss, m, 64);
    // sqrt(log2 e) folded into both Q and K => QK^T lands in exp2 domain
    const float rn = 1.2011224087864498f / sqrtf(fmaxf(ss, 1e-24f));
    us8 nrm, raw;
    nrm[0]=f2bf(a.x*rn);  nrm[1]=f2bf(a.y*rn);  nrm[2]=f2bf(a.z*rn);  nrm[3]=f2bf(a.w*rn);
    nrm[4]=f2bf(bb.x*rn); nrm[5]=f2bf(bb.y*rn); nrm[6]=f2bf(bb.z*rn); nrm[7]=f2bf(bb.w*rn);
    raw[0]=f2bf(a.x);  raw[1]=f2bf(a.y);  raw[2]=f2bf(a.z);  raw[3]=f2bf(a.w);
    raw[4]=f2bf(bb.x); raw[5]=f2bf(bb.y); raw[6]=f2bf(bb.z); raw[7]=f2bf(bb.w);
    *(us8*)(xn + (row0 + r) * DIM + lane * 8) = nrm;
    *(us8*)(&tile[r][lane * 8]) = raw;
  }
  __syncthreads();
#pragma unroll
  for (int pass = 0; pass < 2; ++pass) {
    const int d = pass * 256 + tid;
    ushort_t* dst = vt + ((size_t)b * DIM + d) * SEQ + (size_t)nt * 64;
#pragma unroll
    for (int g = 0; g < 8; ++g) {
      us8 v;
#pragma unroll
      for (int e = 0; e < 8; ++e) v[e] = tile[g * 8 + e][d];  // 2-way bank (free)
      *(us8*)(dst + g * 8) = v;
    }
  }
}

// ---------- kernel 2: fused flash ContraNorm, 32x32x16 MFMA ----------
// 256 blocks (b=bid&7 XCD-affine, qtile=bid>>3), 512 thr = 8 waves.
// wave w: kw=w&1 (key half), qw=(w>>1)&1 (q half, QK), kd=w>>2 (d half, QK).
// No-max softmax (cos-sims bounded): P = exp2(S), l = running sum only.
// LDS: Kbuf dbuf 2x64KB | P [64][64]bf16 8KB | Sp 4x4KB f32 | lsum 512B.
__launch_bounds__(512, 2)
__global__ void k_attn(const ushort_t* __restrict__ xn, const ushort_t* __restrict__ vt,
                       const float* __restrict__ x, float* __restrict__ out) {
  extern __shared__ char smem[];
  char* const Kb0 = smem;
  char* const Kb1 = smem + 65536;
  ushort_t* const P = (ushort_t*)(smem + 131072);
  float* const Sp   = (float*)(smem + 139264);
  float* const lsum = (float*)(smem + 155648);

  const int tid = threadIdx.x;
  const int lane = tid & 63, w = tid >> 6;
  const int kw = w & 1, qw = (w >> 1) & 1, kd = w >> 2;
  const int l31 = lane & 31, l5 = lane >> 5, l7 = lane & 7;
  const int b = blockIdx.x & 7, qt0 = blockIdx.x >> 3;
  const int q0 = qt0 * 64;

  const ushort_t* xnb = xn + (size_t)b * SEQ * DIM;
  const ushort_t* vtb = vt + (size_t)b * DIM * SEQ;

  // Q B-fragments (col = l31 -> q row q0+qw*32+l31), d-half kd: 64 VGPR
  bf16x8 qreg[16];
#pragma unroll
  for (int ks = 0; ks < 16; ++ks)
    qreg[ks] = *(const bf16x8*)(xnb + (size_t)(q0 + qw * 32 + l31) * DIM
                                + kd * 256 + ks * 16 + l5 * 8);

  f32x16 acc[2][2] = {};  // [qt][dt] : O[q 64][d: w*64 + dt*32 + l31]
  float plsum = 0.f;

  // prologue: stage K tile 0 (swizzled source: dest chunk l <- src chunk l^row&7)
#pragma unroll
  for (int i = 0; i < 8; ++i) {
    const int row = w * 8 + i;
    gload_lds16(xnb + (size_t)row * DIM + ((lane ^ i) << 3), Kb0 + row * 1024);
  }
  asm volatile("s_waitcnt vmcnt(0)" ::: "memory");
  __builtin_amdgcn_s_barrier();
  __builtin_amdgcn_sched_barrier(0);

  for (int t = 0; t < NIT; ++t) {
    const int k0 = t * KBLK;
    char* const Kc = (t & 1) ? Kb1 : Kb0;
    char* const Kn = (t & 1) ? Kb0 : Kb1;

    // ---- QK^T partial over d-half: S'[key][q] ----
    f32x16 accS = {};
    const int arow = kw * 32 + l31;
#pragma unroll
    for (int ks = 0; ks < 16; ++ks) {
      const int c = kd * 32 + ks * 2 + l5;
      bf16x8 af = *(const bf16x8*)(Kc + arow * 1024 + ((c ^ l7) << 4));
      accS = __builtin_amdgcn_mfma_f32_32x32x16_bf16(af, qreg[ks], accS, 0, 0, 0);
    }

    // kd==1: export partial S to Sp (f32, 8B-unit XOR swizzle, ~4-way)
    if (kd) {
      float* tile = Sp + (kw * 2 + qw) * 1024 + l31 * 32;
#pragma unroll
      for (int j = 0; j < 8; ++j) {
        const int u = (j & 1) + 4 * (j >> 1) + 2 * l5;
        f32x2 v = { accS[2 * j], accS[2 * j + 1] };
        *(f32x2*)(tile + ((u ^ l7) << 1)) = v;
      }
    }
    WAIT_LGKM_BAR();

    // V fragments direct from L2 (V^T per batch = 2MB, XCD-resident)
    bf16x8 vv[2][4];
#pragma unroll
    for (int dt = 0; dt < 2; ++dt)
#pragma unroll
      for (int ks = 0; ks < 4; ++ks)
        vv[dt][ks] = *(const bf16x8*)(vtb + (size_t)(w * 64 + dt * 32 + l31) * SEQ
                                      + k0 + ks * 16 + l5 * 8);

    if (!kd) {
      // finalize: S = own + partner partial; P = exp2(S); pack bf16 -> P (swizzled)
      const float* tile = Sp + (kw * 2 + qw) * 1024 + l31 * 32;
      uint32_t* prow = (uint32_t*)(P + (qw * 32 + l31) * 64);
#pragma unroll
      for (int j = 0; j < 8; ++j) {
        const int u = (j & 1) + 4 * (j >> 1) + 2 * l5;
        f32x2 o = *(const f32x2*)(tile + ((u ^ l7) << 1));
        float p0 = __builtin_amdgcn_exp2f(accS[2 * j]     + o[0]);
        float p1 = __builtin_amdgcn_exp2f(accS[2 * j + 1] + o[1]);
        plsum += p0 + p1;
        const int chunk = (kw * 4 + (j >> 1)) ^ l7;
        prow[chunk * 4 + (j & 1) + 2 * l5] = packbf(p0, p1);
      }
    } else if (t + 1 < NIT) {
      // kd==1: stage next K tile while kd==0 finalizes
      const int sid = w - 4;
#pragma unroll
      for (int i = 0; i < 16; ++i) {
        const int row = sid * 16 + i;
        gload_lds16(xnb + (size_t)(k0 + KBLK + row) * DIM + ((lane ^ (i & 7)) << 3),
                    Kn + row * 1024);
      }
    }
    WAIT_LGKM_BAR();

    // ---- PV: O[q][d], this wave's 64-d slice ----
#pragma unroll
    for (int qt = 0; qt < 2; ++qt) {
#pragma unroll
      for (int ks = 0; ks < 4; ++ks) {
        const int c = (ks * 2 + l5) ^ l7;
        bf16x8 pa = *(const bf16x8*)(P + (qt * 32 + l31) * 64 + c * 8);
        acc[qt][0] = __builtin_amdgcn_mfma_f32_32x32x16_bf16(pa, vv[0][ks], acc[qt][0], 0, 0, 0);
        acc[qt][1] = __builtin_amdgcn_mfma_f32_32x32x16_bf16(pa, vv[1][ks], acc[qt][1], 0, 0, 0);
      }
    }
    WAIT_ALL_BAR();  // also guarantees K stage(t+1) landed
  }

  // ---- epilogue ----
  if (!kd) {
    plsum += __shfl_xor(plsum, 32, 64);
    if (lane < 32) lsum[kw * 64 + qw * 32 + lane] = plsum;
  }
  // dump acc -> obuf [64 q][512 d] f32 (reuse K buffers), chunk16 swizzle c^= q&7
  float* obuf = (float*)smem;
#pragma unroll
  for (int qt = 0; qt < 2; ++qt)
#pragma unroll
    for (int dt = 0; dt < 2; ++dt) {
      const int d = w * 64 + dt * 32 + l31;
#pragma unroll
      for (int r = 0; r < 16; ++r) {
        const int q = qt * 32 + (r & 3) + 8 * (r >> 2) + 4 * l5;
        const int c = (d >> 2) ^ (q & 7);
        obuf[q * 512 + c * 4 + (d & 3)] = acc[qt][dt][r];
      }
    }
  WAIT_LGKM_BAR();

  const int q = tid >> 3, seg = tid & 7;
  const float s = 0.2f / (lsum[q] + lsum[64 + q]);
  const size_t grow = ((size_t)b * SEQ + q0 + q) * DIM;
#pragma unroll
  for (int i = 0; i < 16; ++i) {
    const int c = seg * 16 + i;
    const int cs = c ^ (q & 7);
    f32x4 a = *(const f32x4*)(obuf + q * 512 + cs * 4);
    const float4 xv = *(const float4*)(x + grow + c * 4);
    float4 o;
    o.x = 1.2f * xv.x - s * a[0];
    o.y = 1.2f * xv.y - s * a[1];
    o.z = 1.2f * xv.z - s * a[2];
    o.w = 1.2f * xv.w - s * a[3];
    *(float4*)(out + grow + c * 4) = o;
  }
}

extern "C" void kernel_launch(void* const* d_in, const int* in_sizes, int n_in,
                              void* d_out, int out_size, void* d_ws, size_t ws_size,
                              hipStream_t stream) {
  const float* x = (const float*)d_in[0];
  float* out = (float*)d_out;
  ushort_t* xn = (ushort_t*)d_ws;                                          // 16 MB
  ushort_t* vt = (ushort_t*)((char*)d_ws + (size_t)BATCH * SEQ * DIM * 2); // 16 MB

  k_prep<<<BATCH * (SEQ / 64), 256, 0, stream>>>(x, xn, vt);
  (void)hipFuncSetAttribute((const void*)k_attn,
                            hipFuncAttributeMaxDynamicSharedMemorySize, LDS_TOTAL);
  k_attn<<<BATCH * SEQ / 64, 512, LDS_TOTAL, stream>>>(xn, vt, x, out);
}

// Round 3
// 221.976 us; speedup vs baseline: 1.2340x; 1.0198x over previous
//
#include <hip/hip_runtime.h>
#include <stdint.h>

typedef unsigned short ushort_t;
typedef unsigned int u32x2 __attribute__((ext_vector_type(2)));
typedef float f32x2 __attribute__((ext_vector_type(2)));
typedef float f32x4 __attribute__((ext_vector_type(4)));
typedef float f32x16 __attribute__((ext_vector_type(16)));
typedef short bf16x8 __attribute__((ext_vector_type(8)));
typedef unsigned short us8 __attribute__((ext_vector_type(8)));

#define AS3 __attribute__((address_space(3)))

#define BATCH 8
#define SEQ   2048
#define DIM   512
#define KBLK  64
#define NIT   (SEQ / KBLK)
#define LDS_TOTAL 155648   // Kdbuf 131072 | P 8192 | Sp 16384 (lsum overlays Sp)

__device__ __forceinline__ ushort_t f2bf(float f) {
  union { float f; uint32_t u; } c; c.f = f;
  uint32_t u = c.u;
  return (ushort_t)((u + 0x7FFFu + ((u >> 16) & 1u)) >> 16);  // RNE
}
__device__ __forceinline__ uint32_t packbf(float a, float b) {
  return (uint32_t)f2bf(a) | ((uint32_t)f2bf(b) << 16);
}
__device__ __forceinline__ void gload_lds16(const void* g, void* l) {
  __builtin_amdgcn_global_load_lds(
      (const AS3 unsigned int*)0 == 0 ? (const __attribute__((address_space(1))) unsigned int*)g
                                      : (const __attribute__((address_space(1))) unsigned int*)g,
      (AS3 unsigned int*)l, 16, 0, 0);
}
#define WAIT_LGKM_BAR() { asm volatile("s_waitcnt lgkmcnt(0)" ::: "memory"); \
  __builtin_amdgcn_s_barrier(); __builtin_amdgcn_sched_barrier(0); }
#define WAIT_ALL_BAR()  { asm volatile("s_waitcnt vmcnt(0) lgkmcnt(0)" ::: "memory"); \
  __builtin_amdgcn_s_barrier(); __builtin_amdgcn_sched_barrier(0); }

// ---------- kernel 1: L2-normalize -> xn bf16 (scaled by sqrt(log2 e)); irn[row] ----------
__global__ void k_prep(const float* __restrict__ x, ushort_t* __restrict__ xn,
                       float* __restrict__ irn) {
  const int lane = threadIdx.x & 63;
  const int w    = threadIdx.x >> 6;
  const size_t row = (size_t)blockIdx.x * 4 + w;   // 16384 rows
  const float* xr = x + row * DIM;
  const float4 a = ((const float4*)xr)[lane * 2];
  const float4 b = ((const float4*)xr)[lane * 2 + 1];
  float ss = a.x*a.x + a.y*a.y + a.z*a.z + a.w*a.w
           + b.x*b.x + b.y*b.y + b.z*b.z + b.w*b.w;
#pragma unroll
  for (int m = 32; m >= 1; m >>= 1) ss += __shfl_xor(ss, m, 64);
  const float nrm2 = sqrtf(fmaxf(ss, 1e-24f));
  const float rn = 1.2011224087864498f / nrm2;     // sqrt(log2 e) folded both sides
  us8 o;
  o[0] = f2bf(a.x*rn); o[1] = f2bf(a.y*rn); o[2] = f2bf(a.z*rn); o[3] = f2bf(a.w*rn);
  o[4] = f2bf(b.x*rn); o[5] = f2bf(b.y*rn); o[6] = f2bf(b.z*rn); o[7] = f2bf(b.w*rn);
  *(us8*)(xn + row * DIM + lane * 8) = o;
  if (lane == 0) irn[row] = nrm2 / 1.2011224087864498f;  // 1/rn : V = xn * irn
}

// ---------- kernel 2: fused flash ContraNorm; V == K tile (irn folded into P) ----------
// 256 blocks (b=bid&7 XCD-affine), 512 thr = 8 waves (kw, qw, kd).
// K LDS layout: subtiled [16 kblk][32 dblk][4 kin][16 din] bf16 (64KB/tile, dbuf).
//   QK A-frag: b128 at ((kblk*32+dblk)<<7)+(kin<<5)+(l5<<4)
//   PV B-frag: 2x ds_read_b64_tr_b16 (column of 4x16 subtile), offset:4096 = next kblk.
__global__ __launch_bounds__(512, 2)
void k_attn(const ushort_t* __restrict__ xn, const float* __restrict__ irn,
            const float* __restrict__ x, float* __restrict__ out) {
  extern __shared__ char smem[];
  char* const Kb0 = smem;
  char* const Kb1 = smem + 65536;
  char* const Pl  = smem + 131072;            // [64 q][64 k] bf16, chunk-XOR swizzled
  float* const Sp = (float*)(smem + 139264);  // [8 slot][4 p][2 l5][32 l31] f32x2
  float* const lsum = (float*)(smem + 139264);// overlays Sp after last use

  const int tid = threadIdx.x;
  const int lane = tid & 63, w = tid >> 6;
  const int kw = w & 1, qw = (w >> 1) & 1, kd = w >> 2;
  const int l31 = lane & 31, l5 = lane >> 5;
  const int b = blockIdx.x & 7, qt0 = blockIdx.x >> 3;
  const int q0 = qt0 * 64;

  const ushort_t* xnb = xn + (size_t)b * SEQ * DIM;
  const float*    irb = irn + (size_t)b * SEQ;

  // Q B-fragments: q col = q0 + qw*32 + l31, d-half kd (16 ksteps): 64 VGPR
  bf16x8 qreg[16];
#pragma unroll
  for (int ks = 0; ks < 16; ++ks)
    qreg[ks] = *(const bf16x8*)(xnb + (size_t)(q0 + qw * 32 + l31) * DIM
                                + kd * 256 + ks * 16 + l5 * 8);

  f32x16 acc[2][2] = {};   // [qt][dt] : O[q0+qt*32+row][w*64 + dt*32 + l31]
  float plsum = 0.f;

  const int kblkA = (kw * 32 + l31) >> 2, kinA = (kw * 32 + l31) & 3;
  const int fb = kd * 8;          // finalize-half regs base (keys kd*16..)
  const int wb = (kd ^ 1) * 8;    // write-half regs base (partner's finalize keys)
  const int slotW = ((kw * 2 + qw) * 2 + kd);
  const int slotR = ((kw * 2 + qw) * 2 + (kd ^ 1));

  auto stage = [&](int k0, char* Kb) {
#pragma unroll
    for (int i = 0; i < 8; ++i) {
      const int c = i * 512 + tid;
      const int k = ((c >> 8) << 2) + ((c >> 1) & 3);
      const int dblk = (c >> 3) & 31, dh = c & 1;
      gload_lds16(xnb + (size_t)(k0 + k) * DIM + dblk * 16 + dh * 8, Kb + c * 16);
    }
  };

  stage(0, Kb0);
  asm volatile("s_waitcnt vmcnt(0)" ::: "memory");
  __builtin_amdgcn_s_barrier();
  __builtin_amdgcn_sched_barrier(0);

  for (int t = 0; t < NIT; ++t) {
    const int k0 = t * KBLK;
    char* const Kc = (t & 1) ? Kb1 : Kb0;
    char* const Kn = (t & 1) ? Kb0 : Kb1;
    const uint kcb = (uint)(uintptr_t)(AS3 char*)Kc;

    // phase 0: issue next-tile staging (hidden under whole iteration)
    if (t + 1 < NIT) stage(k0 + KBLK, Kn);
    // irn values for this wave's finalize half (compiler hides latency under QK)
    const f32x4 i0 = *(const f32x4*)(irb + k0 + kw * 32 + kd * 16 + 4 * l5);
    const f32x4 i1 = *(const f32x4*)(irb + k0 + kw * 32 + kd * 16 + 4 * l5 + 8);

    // phase 1: QK^T  S'[key][q] partial over d-half kd
    f32x16 accS = {};
#pragma unroll
    for (int ks = 0; ks < 16; ++ks) {
      const bf16x8 af = *(const bf16x8*)(Kc + (((kblkA * 32 + kd * 16 + ks) << 7)
                                               + (kinA << 5) + (l5 << 4)));
      accS = __builtin_amdgcn_mfma_f32_32x32x16_bf16(af, qreg[ks], accS, 0, 0, 0);
    }

    // phase 2: write partner's partial half (8 regs) to Sp
#pragma unroll
    for (int p = 0; p < 4; ++p) {
      f32x2 v = { accS[wb + 2 * p], accS[wb + 2 * p + 1] };
      *(f32x2*)(Sp + ((slotW * 4 + p) * 2 + l5) * 64 + l31 * 2) = v;
    }
    WAIT_LGKM_BAR();

    // phase 3: finalize own half: S = own + partner; e = exp2(S); P = e * irn
    const float ir[8] = { i0[0], i0[1], i0[2], i0[3], i1[0], i1[1], i1[2], i1[3] };
    uint32_t* prow = (uint32_t*)(Pl + (size_t)(qw * 32 + l31) * 128);
#pragma unroll
    for (int p = 0; p < 4; ++p) {
      const f32x2 o = *(const f32x2*)(Sp + ((slotR * 4 + p) * 2 + l5) * 64 + l31 * 2);
      const float e0 = __builtin_amdgcn_exp2f(accS[fb + 2 * p]     + o[0]);
      const float e1 = __builtin_amdgcn_exp2f(accS[fb + 2 * p + 1] + o[1]);
      plsum += e0 + e1;
      const int chunk = (kw * 4 + kd * 2 + (p >> 1)) ^ (l31 & 7);
      prow[chunk * 4 + (p & 1) + 2 * l5] = packbf(e0 * ir[2 * p], e1 * ir[2 * p + 1]);
    }
    WAIT_LGKM_BAR();

    // phase 4: PV from P (A) and Kc-as-V (B via tr reads), d-slice = w*64
#pragma unroll
    for (int ks = 0; ks < 4; ++ks) {
      const bf16x8 pa0 = *(const bf16x8*)(Pl + (size_t)(0 * 32 + l31) * 128
                                          + ((((ks * 2 + l5) ^ (l31 & 7))) << 4));
      const bf16x8 pa1 = *(const bf16x8*)(Pl + (size_t)(1 * 32 + l31) * 128
                                          + ((((ks * 2 + l5) ^ (l31 & 7))) << 4));
      union { u32x2 u[2]; bf16x8 v; } B0, B1;
      const int kblk1 = ks * 4 + l5 * 2;
      {
        const uint a0 = kcb + (((kblk1 * 32 + (w * 4 + 0 * 2 + (l31 >> 4))) << 7)
                               + ((l31 & 15) << 3));
        asm volatile("ds_read_b64_tr_b16 %0, %1" : "=v"(B0.u[0]) : "v"(a0));
        asm volatile("ds_read_b64_tr_b16 %0, %1 offset:4096" : "=v"(B0.u[1]) : "v"(a0));
        const uint a1 = kcb + (((kblk1 * 32 + (w * 4 + 1 * 2 + (l31 >> 4))) << 7)
                               + ((l31 & 15) << 3));
        asm volatile("ds_read_b64_tr_b16 %0, %1" : "=v"(B1.u[0]) : "v"(a1));
        asm volatile("ds_read_b64_tr_b16 %0, %1 offset:4096" : "=v"(B1.u[1]) : "v"(a1));
      }
      asm volatile("s_waitcnt lgkmcnt(0)" ::: "memory");
      __builtin_amdgcn_sched_barrier(0);
      acc[0][0] = __builtin_amdgcn_mfma_f32_32x32x16_bf16(pa0, B0.v, acc[0][0], 0, 0, 0);
      acc[0][1] = __builtin_amdgcn_mfma_f32_32x32x16_bf16(pa0, B1.v, acc[0][1], 0, 0, 0);
      acc[1][0] = __builtin_amdgcn_mfma_f32_32x32x16_bf16(pa1, B0.v, acc[1][0], 0, 0, 0);
      acc[1][1] = __builtin_amdgcn_mfma_f32_32x32x16_bf16(pa1, B1.v, acc[1][1], 0, 0, 0);
    }
    WAIT_ALL_BAR();   // drains stage(t+1) too
  }

  // ---- epilogue ----
  plsum += __shfl_xor(plsum, 32, 64);
  if (lane < 32) lsum[(kw * 2 + kd) * 64 + qw * 32 + l31] = plsum;

  float* obuf = (float*)smem;   // [64 q][512 d], chunk4 swizzle c ^= q&7 (K dead)
#pragma unroll
  for (int qt = 0; qt < 2; ++qt)
#pragma unroll
    for (int dt = 0; dt < 2; ++dt) {
      const int d = w * 64 + dt * 32 + l31;
#pragma unroll
      for (int r = 0; r < 16; ++r) {
        const int q = qt * 32 + (r & 3) + 8 * (r >> 2) + 4 * l5;
        const int c = (d >> 2) ^ (q & 7);
        obuf[q * 512 + c * 4 + (d & 3)] = acc[qt][dt][r];
      }
    }
  WAIT_LGKM_BAR();

  const int q = tid >> 3, seg = tid & 7;
  const float s = 0.2f / (lsum[q] + lsum[64 + q] + lsum[128 + q] + lsum[192 + q]);
  const size_t grow = ((size_t)b * SEQ + q0 + q) * DIM;
#pragma unroll
  for (int i = 0; i < 16; ++i) {
    const int c = seg * 16 + i;
    const int cs = c ^ (q & 7);
    f32x4 a = *(const f32x4*)(obuf + q * 512 + cs * 4);
    const float4 xv = *(const float4*)(x + grow + c * 4);
    float4 o;
    o.x = 1.2f * xv.x - s * a[0];
    o.y = 1.2f * xv.y - s * a[1];
    o.z = 1.2f * xv.z - s * a[2];
    o.w = 1.2f * xv.w - s * a[3];
    *(float4*)(out + grow + c * 4) = o;
  }
}

extern "C" void kernel_launch(void* const* d_in, const int* in_sizes, int n_in,
                              void* d_out, int out_size, void* d_ws, size_t ws_size,
                              hipStream_t stream) {
  const float* x = (const float*)d_in[0];
  float* out = (float*)d_out;
  ushort_t* xn = (ushort_t*)d_ws;                                      // 16 MB
  float* irn = (float*)((char*)d_ws + (size_t)BATCH * SEQ * DIM * 2);  // 64 KB

  k_prep<<<BATCH * SEQ / 4, 256, 0, stream>>>(x, xn, irn);
  (void)hipFuncSetAttribute((const void*)k_attn,
                            hipFuncAttributeMaxDynamicSharedMemorySize, LDS_TOTAL);
  k_attn<<<BATCH * SEQ / 64, 512, LDS_TOTAL, stream>>>(xn, irn, x, out);
}